// Round 10
// baseline (693.262 us; speedup 1.0000x reference)
//
#include <hip/hip_runtime.h>
#include <hip/hip_fp16.h>

#define F_IN 256
#define HID 128

typedef _Float16 half8 __attribute__((ext_vector_type(8)));
typedef _Float16 half4v __attribute__((ext_vector_type(4)));
typedef float f32x4 __attribute__((ext_vector_type(4)));
typedef unsigned int uint4v __attribute__((ext_vector_type(4)));

// ---------------- graph preprocessing ----------------

__global__ void k_count2(const int* __restrict__ col_s, int E, int* __restrict__ cnt_s,
                         const int* __restrict__ col_k, int EK, int* __restrict__ cnt_k) {
  int e = blockIdx.x * blockDim.x + threadIdx.x;
  if (e < E) {
    atomicAdd(&cnt_s[col_s[e]], 1);
  } else {
    int f = e - E;
    if (f < EK) atomicAdd(&cnt_k[col_k[f]], 1);
  }
}

__global__ void k_scan_block(const int* __restrict__ in, int n, int* __restrict__ out,
                             int* __restrict__ bsum) {
  __shared__ int s[1024];
  int tid = threadIdx.x;
  int i = blockIdx.x * 1024 + tid;
  int v = (i < n) ? in[i] : 0;
  s[tid] = v;
  __syncthreads();
  for (int off = 1; off < 1024; off <<= 1) {
    int t = (tid >= off) ? s[tid - off] : 0;
    __syncthreads();
    s[tid] += t;
    __syncthreads();
  }
  if (i < n) out[i] = s[tid] - v;          // exclusive
  if (tid == 1023) bsum[blockIdx.x] = s[1023];
}

__global__ void k_scan_single(int* __restrict__ bsum, int nb, int* __restrict__ tail) {
  if (threadIdx.x == 0 && blockIdx.x == 0) {
    int run = 0;
    for (int b = 0; b < nb; ++b) { int t = bsum[b]; bsum[b] = run; run += t; }
    *tail = run;
  }
}

__global__ void k_add_off(int* __restrict__ out, const int* __restrict__ bsum, int n) {
  int i = blockIdx.x * blockDim.x + threadIdx.x;
  if (i < n) out[i] += bsum[i >> 10];
}

__global__ void k_scatter2(const int* __restrict__ row_s, const int* __restrict__ col_s, int E,
                           const int* __restrict__ offs_s, int* __restrict__ cur_s,
                           int* __restrict__ csr_s,
                           const int* __restrict__ row_k, const int* __restrict__ col_k, int EK,
                           const int* __restrict__ offs_k, int* __restrict__ cur_k,
                           int* __restrict__ csr_k) {
  int e = blockIdx.x * blockDim.x + threadIdx.x;
  if (e < E) {
    int c = col_s[e];
    int p = offs_s[c] + atomicAdd(&cur_s[c], 1);
    csr_s[p] = row_s[e];
  } else {
    int f = e - E;
    if (f < EK) {
      int c = col_k[f];
      int p = offs_k[c] + atomicAdd(&cur_k[c], 1);
      csr_k[p] = row_k[f];
    }
  }
}

// ---------------- W fp32 -> fp16 (all three, concatenated) ----------------

__global__ void k_cvt_w(const float* __restrict__ W0, const float* __restrict__ W1,
                        const float* __restrict__ W2, _Float16* __restrict__ Wh) {
  const int sz = HID * F_IN;                    // 32768
  int idx = (blockIdx.x * 256 + threadIdx.x) * 4;  // [0, 3*sz)
  const float* src = (idx < sz) ? (W0 + idx)
                   : (idx < 2 * sz) ? (W1 + idx - sz)
                   : (W2 + idx - 2 * sz);
  float4 v = *(const float4*)src;
  half4v o;
  o[0] = (_Float16)v.x; o[1] = (_Float16)v.y; o[2] = (_Float16)v.z; o[3] = (_Float16)v.w;
  *(half4v*)(Wh + idx) = o;
}

// ---------------- fused MFMA GEMM, m97-style LDS double-buffered (unchanged) ----------------

__device__ inline half8 cvt8(float4 a, float4 b) {
  half8 v;
  v[0] = (_Float16)a.x; v[1] = (_Float16)a.y; v[2] = (_Float16)a.z; v[3] = (_Float16)a.w;
  v[4] = (_Float16)b.x; v[5] = (_Float16)b.y; v[6] = (_Float16)b.z; v[7] = (_Float16)b.w;
  return v;
}

__global__ __launch_bounds__(256, 3) void k_gemm3(
    const float* __restrict__ x, const _Float16* __restrict__ Wh,
    const float* __restrict__ b0, const float* __restrict__ b1, const float* __restrict__ b2,
    int n, const int* __restrict__ cnt_s, const int* __restrict__ cnt_k,
    _Float16* __restrict__ gS1, _Float16* __restrict__ gS2,
    _Float16* __restrict__ gF2s, _Float16* __restrict__ gF2k)
{
  __shared__ __align__(16) char lds[49152];  // A0@0 A1@8192 B0@16384 B1@32768
  int tid = threadIdx.x;
  int m0 = blockIdx.x * 64;

  int rA = tid >> 2;
  int cA0 = (tid & 3) * 2, cA1 = cA0 + 1;
  int gnA = m0 + rA; if (gnA >= n) gnA = n - 1;
  const float* xA = x + (size_t)gnA * F_IN;
  unsigned aw0 = (unsigned)(rA * 128 + ((cA0 ^ (rA & 7)) << 4));
  unsigned aw1 = (unsigned)(rA * 128 + ((cA1 ^ (rA & 7)) << 4));
  int rB = tid >> 1;
  int cB0 = (tid & 1) * 4;
  unsigned bw[4];
#pragma unroll
  for (int i = 0; i < 4; ++i)
    bw[i] = (unsigned)(rB * 128 + (((cB0 + i) ^ (rB & 7)) << 4));

  int lane = tid & 63;
  int wv = tid >> 6;
  int wm = wv >> 1, wn = wv & 1;
  int l15 = lane & 15, lhi = lane >> 4;
  unsigned koff0 = (unsigned)(((0 * 4 + lhi) ^ (l15 & 7)) << 4);
  unsigned koff1 = (unsigned)(((1 * 4 + lhi) ^ (l15 & 7)) << 4);
  unsigned raw0 = (unsigned)((wm * 32 + 0 * 16 + l15) * 128);
  unsigned raw1 = (unsigned)((wm * 32 + 1 * 16 + l15) * 128);
  unsigned rbw[4];
#pragma unroll
  for (int ni = 0; ni < 4; ++ni)
    rbw[ni] = (unsigned)((wn * 64 + ni * 16 + l15) * 128);

  int nodebase = m0 + wm * 32 + l15;
  float ss[2], sk[2];
#pragma unroll
  for (int mi = 0; mi < 2; ++mi) {
    int nd = nodebase + mi * 16;
    int cn = (nd < n) ? nd : (n - 1);
    ss[mi] = rsqrtf((float)(cnt_s[cn] + 1));
    sk[mi] = rsqrtf((float)(cnt_k[cn] + 1));
  }

#pragma unroll 1
  for (int w = 0; w < 3; ++w) {
    const float* bias = (w == 0) ? b0 : (w == 1) ? b1 : b2;
    _Float16* dst = (w == 0) ? gS1 : (w == 1) ? gS2 : gF2s;
    const _Float16* WB = Wh + (size_t)w * (HID * F_IN) + (size_t)rB * F_IN;

    f32x4 acc[2][4];
#pragma unroll
    for (int ni = 0; ni < 4; ++ni) {
      float4 bv = *(const float4*)(bias + wn * 64 + ni * 16 + lhi * 4);
      f32x4 b4 = {bv.x, bv.y, bv.z, bv.w};
      acc[0][ni] = b4; acc[1][ni] = b4;
    }

    float4 fa[4]; uint4v ub[4];
    fa[0] = *(const float4*)(xA + 0 * 64 + cA0 * 8);
    fa[1] = *(const float4*)(xA + 0 * 64 + cA0 * 8 + 4);
    fa[2] = *(const float4*)(xA + 0 * 64 + cA1 * 8);
    fa[3] = *(const float4*)(xA + 0 * 64 + cA1 * 8 + 4);
#pragma unroll
    for (int i = 0; i < 4; ++i)
      ub[i] = *(const uint4v*)(WB + 0 * 64 + (cB0 + i) * 8);

#pragma unroll
    for (int kt = 0; kt < 4; ++kt) {
      char* Ab = lds + (kt & 1) * 8192;
      char* Bb = lds + 16384 + (kt & 1) * 16384;
      *(half8*)(Ab + aw0) = cvt8(fa[0], fa[1]);
      *(half8*)(Ab + aw1) = cvt8(fa[2], fa[3]);
#pragma unroll
      for (int i = 0; i < 4; ++i) *(uint4v*)(Bb + bw[i]) = ub[i];
      if (kt < 3) {
        fa[0] = *(const float4*)(xA + (kt + 1) * 64 + cA0 * 8);
        fa[1] = *(const float4*)(xA + (kt + 1) * 64 + cA0 * 8 + 4);
        fa[2] = *(const float4*)(xA + (kt + 1) * 64 + cA1 * 8);
        fa[3] = *(const float4*)(xA + (kt + 1) * 64 + cA1 * 8 + 4);
#pragma unroll
        for (int i = 0; i < 4; ++i)
          ub[i] = *(const uint4v*)(WB + (kt + 1) * 64 + (cB0 + i) * 8);
      }
      __syncthreads();
      {
        const char* Ar = Ab; const char* Br = Bb;
#pragma unroll
        for (int ks = 0; ks < 2; ++ks) {
          unsigned ko = ks ? koff1 : koff0;
          half8 xf0 = *(const half8*)(Ar + raw0 + ko);
          half8 xf1 = *(const half8*)(Ar + raw1 + ko);
          half8 wf0 = *(const half8*)(Br + rbw[0] + ko);
          half8 wf1 = *(const half8*)(Br + rbw[1] + ko);
          half8 wf2 = *(const half8*)(Br + rbw[2] + ko);
          half8 wf3 = *(const half8*)(Br + rbw[3] + ko);
          acc[0][0] = __builtin_amdgcn_mfma_f32_16x16x32_f16(wf0, xf0, acc[0][0], 0, 0, 0);
          acc[0][1] = __builtin_amdgcn_mfma_f32_16x16x32_f16(wf1, xf0, acc[0][1], 0, 0, 0);
          acc[0][2] = __builtin_amdgcn_mfma_f32_16x16x32_f16(wf2, xf0, acc[0][2], 0, 0, 0);
          acc[0][3] = __builtin_amdgcn_mfma_f32_16x16x32_f16(wf3, xf0, acc[0][3], 0, 0, 0);
          acc[1][0] = __builtin_amdgcn_mfma_f32_16x16x32_f16(wf0, xf1, acc[1][0], 0, 0, 0);
          acc[1][1] = __builtin_amdgcn_mfma_f32_16x16x32_f16(wf1, xf1, acc[1][1], 0, 0, 0);
          acc[1][2] = __builtin_amdgcn_mfma_f32_16x16x32_f16(wf2, xf1, acc[1][2], 0, 0, 0);
          acc[1][3] = __builtin_amdgcn_mfma_f32_16x16x32_f16(wf3, xf1, acc[1][3], 0, 0, 0);
        }
      }
    }

#pragma unroll
    for (int mi = 0; mi < 2; ++mi) {
      int nd = nodebase + mi * 16;
      if (nd < n) {
        size_t ob = (size_t)nd * HID + wn * 64 + lhi * 4;
        float s1 = ss[mi];
#pragma unroll
        for (int ni = 0; ni < 4; ++ni) {
          half4v o;
          o[0] = (_Float16)(acc[mi][ni][0] * s1); o[1] = (_Float16)(acc[mi][ni][1] * s1);
          o[2] = (_Float16)(acc[mi][ni][2] * s1); o[3] = (_Float16)(acc[mi][ni][3] * s1);
          *(half4v*)(dst + ob + ni * 16) = o;
        }
        if (w == 2) {
          float s2 = sk[mi];
#pragma unroll
          for (int ni = 0; ni < 4; ++ni) {
            half4v o2;
            o2[0] = (_Float16)(acc[mi][ni][0] * s2); o2[1] = (_Float16)(acc[mi][ni][1] * s2);
            o2[2] = (_Float16)(acc[mi][ni][2] * s2); o2[3] = (_Float16)(acc[mi][ni][3] * s2);
            *(half4v*)(gF2k + ob + ni * 16) = o2;
          }
        }
      }
    }
  }
}

// ---------------- SpMM (fp16 features, deep-MLP uniform gather loops) ----------------
// One wave per dest node. g = lane>>4 (edge slot), c = lane&15 (16B chunk).
// All gathers of an iteration are issued as NAMED loads followed by
// sched_barrier(0) (pins issue order - compiler otherwise sinks loads to
// minimize VGPR, round-9 evidence: spmm3 VGPR=40 < live-load requirement).
// Pad slots gather row w (L1-hot) and are counted; epilogue adds
// (1-padtot)*g[w] for exactness.
// mode 0: *1/deg -> fp16; mode 1: *rsqrt(deg) -> fp32; mode 2: mode1 + addsrc.

__device__ inline float2 h2f2(unsigned int u) {
  __half2 h; *(unsigned int*)&h = u; return __half22float2(h);
}

__global__ __launch_bounds__(256, 4) void k_spmm_h(
    const _Float16* __restrict__ gin, void* __restrict__ gout,
    const int* __restrict__ csr, const int* __restrict__ offs, const int* __restrict__ cnt,
    int n, int mode, const float* __restrict__ addsrc)
{
  int w = (blockIdx.x << 2) | ((int)threadIdx.x >> 6);
  if (w >= n) return;
  int lane = threadIdx.x & 63;
  int g = lane >> 4;
  int c = lane & 15;
  int beg = offs[w], end = offs[w + 1];

  float acc[8];
#pragma unroll
  for (int i = 0; i < 8; ++i) acc[i] = 0.f;
  int padc = 0;
  const size_t selfoff = ((size_t)w << 7) + c * 8;

#pragma unroll 1
  for (int e = beg; e < end; e += 24) {
    uint4v u0, u1, u2, u3, u4, u5;
#define LDH(k, reg)                                                              \
    {                                                                            \
      int pos = e + 4 * k + g;                                                   \
      int idx = w;                                                               \
      if (pos < end) idx = csr[pos]; else ++padc;                                \
      reg = *(const uint4v*)(gin + ((size_t)(unsigned)idx << 7) + c * 8);        \
    }
    LDH(0, u0) LDH(1, u1) LDH(2, u2) LDH(3, u3) LDH(4, u4) LDH(5, u5)
#undef LDH
    __builtin_amdgcn_sched_barrier(0);
#define ACCH(reg)                                                                \
    {                                                                            \
      _Pragma("unroll")                                                          \
      for (int q = 0; q < 4; ++q) {                                              \
        float2 v = h2f2(reg[q]);                                                 \
        acc[q * 2] += v.x; acc[q * 2 + 1] += v.y;                                \
      }                                                                          \
    }
    ACCH(u0) ACCH(u1) ACCH(u2) ACCH(u3) ACCH(u4) ACCH(u5)
#undef ACCH
  }

  // reduce across the 4 g-groups (values + pad count)
#pragma unroll
  for (int i = 0; i < 8; ++i) {
    acc[i] += __shfl_xor(acc[i], 16, 64);
    acc[i] += __shfl_xor(acc[i], 32, 64);
  }
  padc += __shfl_xor(padc, 16, 64);
  padc += __shfl_xor(padc, 32, 64);

  // self row with exact pad correction: + (1 - padtot) * g[w]
  {
    float coef = 1.0f - (float)padc;
    uint4v u = *(const uint4v*)(gin + selfoff);
#pragma unroll
    for (int q = 0; q < 4; ++q) {
      float2 v = h2f2(u[q]);
      acc[q * 2] += coef * v.x; acc[q * 2 + 1] += coef * v.y;
    }
  }

  float deg = (float)(cnt[w] + 1);
  if (mode == 0) {
    float sc = 1.0f / deg;
    if (g == 0) {
      uint4v o;
#pragma unroll
      for (int q = 0; q < 4; ++q) {
        __half2 h = __float22half2_rn(make_float2(acc[q * 2] * sc, acc[q * 2 + 1] * sc));
        o[q] = *(unsigned int*)&h;
      }
      *(uint4v*)((_Float16*)gout + selfoff) = o;
    }
  } else {
    float sc = rsqrtf(deg);
    if (g == 0) {
      float o[8];
#pragma unroll
      for (int i = 0; i < 8; ++i) o[i] = acc[i] * sc;
      if (mode == 2) {
        const float* ap = addsrc + ((size_t)w << 7) + c * 8;
        float4 a0 = *(const float4*)ap;
        float4 a1 = *(const float4*)(ap + 4);
        o[0] += a0.x; o[1] += a0.y; o[2] += a0.z; o[3] += a0.w;
        o[4] += a1.x; o[5] += a1.y; o[6] += a1.z; o[7] += a1.w;
      }
      float* op = (float*)gout + ((size_t)w << 7) + c * 8;
      *(float4*)op = make_float4(o[0], o[1], o[2], o[3]);
      *(float4*)(op + 4) = make_float4(o[4], o[5], o[6], o[7]);
    }
  }
}

// 3 feature matrices propagated in one pass over the graph (shared steps 1,2)
__global__ __launch_bounds__(256, 4) void k_spmm3(
    const _Float16* __restrict__ g0, const _Float16* __restrict__ g1,
    const _Float16* __restrict__ g2,
    void* __restrict__ o0, void* __restrict__ o1, void* __restrict__ o2,
    int md0, int md1, int md2,
    const int* __restrict__ csr, const int* __restrict__ offs, const int* __restrict__ cnt,
    int n)
{
  int w = (blockIdx.x << 2) | ((int)threadIdx.x >> 6);
  if (w >= n) return;
  int lane = threadIdx.x & 63;
  int g = lane >> 4;
  int c = lane & 15;
  int beg = offs[w], end = offs[w + 1];

  float a0[8], a1[8], a2[8];
#pragma unroll
  for (int i = 0; i < 8; ++i) { a0[i] = 0.f; a1[i] = 0.f; a2[i] = 0.f; }
  int padc = 0;

#pragma unroll 1
  for (int e = beg; e < end; e += 12) {
    size_t off0, off1, off2;
#define IDX3(k, offv)                                                            \
    {                                                                            \
      int pos = e + 4 * k + g;                                                   \
      int idx = w;                                                               \
      if (pos < end) idx = csr[pos]; else ++padc;                                \
      offv = ((size_t)(unsigned)idx << 7) + c * 8;                               \
    }
    IDX3(0, off0) IDX3(1, off1) IDX3(2, off2)
#undef IDX3
    uint4v u00 = *(const uint4v*)(g0 + off0);
    uint4v u01 = *(const uint4v*)(g1 + off0);
    uint4v u02 = *(const uint4v*)(g2 + off0);
    uint4v u10 = *(const uint4v*)(g0 + off1);
    uint4v u11 = *(const uint4v*)(g1 + off1);
    uint4v u12 = *(const uint4v*)(g2 + off1);
    uint4v u20 = *(const uint4v*)(g0 + off2);
    uint4v u21 = *(const uint4v*)(g1 + off2);
    uint4v u22 = *(const uint4v*)(g2 + off2);
    __builtin_amdgcn_sched_barrier(0);
#pragma unroll
    for (int q = 0; q < 4; ++q) {
      float2 v;
      v = h2f2(u00[q]); a0[q * 2] += v.x; a0[q * 2 + 1] += v.y;
      v = h2f2(u01[q]); a1[q * 2] += v.x; a1[q * 2 + 1] += v.y;
      v = h2f2(u02[q]); a2[q * 2] += v.x; a2[q * 2 + 1] += v.y;
      v = h2f2(u10[q]); a0[q * 2] += v.x; a0[q * 2 + 1] += v.y;
      v = h2f2(u11[q]); a1[q * 2] += v.x; a1[q * 2 + 1] += v.y;
      v = h2f2(u12[q]); a2[q * 2] += v.x; a2[q * 2 + 1] += v.y;
      v = h2f2(u20[q]); a0[q * 2] += v.x; a0[q * 2 + 1] += v.y;
      v = h2f2(u21[q]); a1[q * 2] += v.x; a1[q * 2 + 1] += v.y;
      v = h2f2(u22[q]); a2[q * 2] += v.x; a2[q * 2 + 1] += v.y;
    }
  }

#pragma unroll
  for (int i = 0; i < 8; ++i) {
    a0[i] += __shfl_xor(a0[i], 16, 64); a0[i] += __shfl_xor(a0[i], 32, 64);
    a1[i] += __shfl_xor(a1[i], 16, 64); a1[i] += __shfl_xor(a1[i], 32, 64);
    a2[i] += __shfl_xor(a2[i], 16, 64); a2[i] += __shfl_xor(a2[i], 32, 64);
  }
  padc += __shfl_xor(padc, 16, 64);
  padc += __shfl_xor(padc, 32, 64);

  // self rows with exact pad correction
  {
    float coef = 1.0f - (float)padc;
    size_t off = ((size_t)w << 7) + c * 8;
    uint4v u0 = *(const uint4v*)(g0 + off);
    uint4v u1 = *(const uint4v*)(g1 + off);
    uint4v u2 = *(const uint4v*)(g2 + off);
#pragma unroll
    for (int q = 0; q < 4; ++q) {
      float2 v;
      v = h2f2(u0[q]); a0[q * 2] += coef * v.x; a0[q * 2 + 1] += coef * v.y;
      v = h2f2(u1[q]); a1[q * 2] += coef * v.x; a1[q * 2 + 1] += coef * v.y;
      v = h2f2(u2[q]); a2[q * 2] += coef * v.x; a2[q * 2 + 1] += coef * v.y;
    }
  }

  float deg = (float)(cnt[w] + 1);
  if (g == 0) {
    float inv = 1.0f / deg, rs = rsqrtf(deg);
    {
      float sc = (md0 == 0) ? inv : rs;
      if (md0 == 0) {
        uint4v o;
#pragma unroll
        for (int q = 0; q < 4; ++q) {
          __half2 h = __float22half2_rn(make_float2(a0[q * 2] * sc, a0[q * 2 + 1] * sc));
          o[q] = *(unsigned int*)&h;
        }
        *(uint4v*)((_Float16*)o0 + ((size_t)w << 7) + c * 8) = o;
      } else {
        float* op = (float*)o0 + ((size_t)w << 7) + c * 8;
        *(float4*)op = make_float4(a0[0] * sc, a0[1] * sc, a0[2] * sc, a0[3] * sc);
        *(float4*)(op + 4) = make_float4(a0[4] * sc, a0[5] * sc, a0[6] * sc, a0[7] * sc);
      }
    }
    {
      float sc = (md1 == 0) ? inv : rs;
      if (md1 == 0) {
        uint4v o;
#pragma unroll
        for (int q = 0; q < 4; ++q) {
          __half2 h = __float22half2_rn(make_float2(a1[q * 2] * sc, a1[q * 2 + 1] * sc));
          o[q] = *(unsigned int*)&h;
        }
        *(uint4v*)((_Float16*)o1 + ((size_t)w << 7) + c * 8) = o;
      } else {
        float* op = (float*)o1 + ((size_t)w << 7) + c * 8;
        *(float4*)op = make_float4(a1[0] * sc, a1[1] * sc, a1[2] * sc, a1[3] * sc);
        *(float4*)(op + 4) = make_float4(a1[4] * sc, a1[5] * sc, a1[6] * sc, a1[7] * sc);
      }
    }
    {
      float sc = (md2 == 0) ? inv : rs;
      if (md2 == 0) {
        uint4v o;
#pragma unroll
        for (int q = 0; q < 4; ++q) {
          __half2 h = __float22half2_rn(make_float2(a2[q * 2] * sc, a2[q * 2 + 1] * sc));
          o[q] = *(unsigned int*)&h;
        }
        *(uint4v*)((_Float16*)o2 + ((size_t)w << 7) + c * 8) = o;
      } else {
        float* op = (float*)o2 + ((size_t)w << 7) + c * 8;
        *(float4*)op = make_float4(a2[0] * sc, a2[1] * sc, a2[2] * sc, a2[3] * sc);
        *(float4*)(op + 4) = make_float4(a2[4] * sc, a2[5] * sc, a2[6] * sc, a2[7] * sc);
      }
    }
  }
}

// ---------------- launch ----------------

extern "C" void kernel_launch(void* const* d_in, const int* in_sizes, int n_in,
                              void* d_out, int out_size, void* d_ws, size_t ws_size,
                              hipStream_t stream) {
  const float* x    = (const float*)d_in[0];
  const int*   ei   = (const int*)d_in[1];
  const int*   knn  = (const int*)d_in[2];
  const float* W_s1 = (const float*)d_in[3];
  const float* b_s1 = (const float*)d_in[4];
  const float* W_s2 = (const float*)d_in[5];
  const float* b_s2 = (const float*)d_in[6];
  const float* W_f2 = (const float*)d_in[7];
  const float* b_f2 = (const float*)d_in[8];

  const int N  = in_sizes[0] / F_IN;
  const int E  = in_sizes[1] / 2;
  const int EK = in_sizes[2] / 2;
  const int* row_s = ei;   const int* col_s = ei + E;
  const int* row_k = knn;  const int* col_k = knn + EK;

  char* p = (char*)d_ws;
  auto carve = [&](size_t bytes) {
    char* r = p; p += (bytes + 511) & ~(size_t)511; return (void*)r;
  };
  int* cnt_s = (int*)carve((size_t)N * 4);
  int* cnt_k = (int*)carve((size_t)N * 4);
  int* cur_s = (int*)carve((size_t)N * 4);
  int* cur_k = (int*)carve((size_t)N * 4);
  char* zero_end = p;
  int* offs_s = (int*)carve((size_t)(N + 1) * 4);
  int* offs_k = (int*)carve((size_t)(N + 1) * 4);
  int* bsum   = (int*)carve(4096);
  int* csr_s  = (int*)carve((size_t)E * 4);
  int* csr_k  = (int*)carve((size_t)EK * 4);
  _Float16* Wh  = (_Float16*)carve((size_t)3 * HID * F_IN * 2);
  _Float16* gS1 = (_Float16*)carve((size_t)N * HID * 2);
  _Float16* gS2 = (_Float16*)carve((size_t)N * HID * 2);
  _Float16* gF2s= (_Float16*)carve((size_t)N * HID * 2);
  _Float16* gF2k= (_Float16*)carve((size_t)N * HID * 2);
  _Float16* tS2 = (_Float16*)carve((size_t)N * HID * 2);

  float* out_h0 = (float*)d_out;
  float* out_h1 = out_h0 + (size_t)N * HID;
  float* out_z0 = out_h1 + (size_t)N * HID;
  float* out_z1 = out_z0 + (size_t)N * HID;
  // z1 region (fp32, N*HID floats = 2x fp16 buffers) is free until the very last
  // launch -> scratch for the two single-use step-1 outputs.
  _Float16* tS1 = (_Float16*)out_z1;
  _Float16* tF2 = tS1 + (size_t)N * HID;

  hipMemsetAsync(d_ws, 0, (size_t)(zero_end - (char*)d_ws), stream);

  const int tpb = 256;
  int etot = E + EK;
  k_count2<<<(etot + tpb - 1) / tpb, tpb, 0, stream>>>(col_s, E, cnt_s, col_k, EK, cnt_k);

  int nb = (N + 1023) / 1024;
  k_scan_block<<<nb, 1024, 0, stream>>>(cnt_s, N, offs_s, bsum);
  k_scan_single<<<1, 64, 0, stream>>>(bsum, nb, offs_s + N);
  k_add_off<<<(N + tpb - 1) / tpb, tpb, 0, stream>>>(offs_s, bsum, N);
  k_scan_block<<<nb, 1024, 0, stream>>>(cnt_k, N, offs_k, bsum);
  k_scan_single<<<1, 64, 0, stream>>>(bsum, nb, offs_k + N);
  k_add_off<<<(N + tpb - 1) / tpb, tpb, 0, stream>>>(offs_k, bsum, N);

  k_scatter2<<<(etot + tpb - 1) / tpb, tpb, 0, stream>>>(
      row_s, col_s, E, offs_s, cur_s, csr_s,
      row_k, col_k, EK, offs_k, cur_k, csr_k);

  k_cvt_w<<<96, 256, 0, stream>>>(W_s1, W_s2, W_f2, Wh);
  k_gemm3<<<(N + 63) / 64, 256, 0, stream>>>(x, Wh, b_s1, b_s2, b_f2, N, cnt_s, cnt_k,
                                             gS1, gS2, gF2s, gF2k);

  int spmm_grid = (N + 3) / 4;

  // step 1 (all chains), step 2 (s1 & f2 finalize, s2 continues)
  k_spmm3<<<spmm_grid, 256, 0, stream>>>(gS1, gS2, gF2s,
                                         tS1, tS2, tF2, 0, 0, 0,
                                         csr_s, offs_s, cnt_s, N);
  k_spmm3<<<spmm_grid, 256, 0, stream>>>(tS1, tS2, tF2,
                                         out_h0, gS1, out_z0, 1, 0, 1,
                                         csr_s, offs_s, cnt_s, N);

  // s2 steps 3..10: ping-pong gS1 <-> tS2
  {
    _Float16* cur = gS1; _Float16* alt = tS2;
    for (int it = 0; it < 7; ++it) {
      k_spmm_h<<<spmm_grid, 256, 0, stream>>>(cur, alt,
                                              csr_s, offs_s, cnt_s, N, 0, nullptr);
      _Float16* t = cur; cur = alt; alt = t;
    }
    k_spmm_h<<<spmm_grid, 256, 0, stream>>>(cur, out_h1,
                                            csr_s, offs_s, cnt_s, N, 1, nullptr);
  }

  // knn step (last: frees the z1 scratch region before writing it)
  k_spmm_h<<<spmm_grid, 256, 0, stream>>>(gF2k, out_z1,
                                          csr_k, offs_k, cnt_k, N, 2,
                                          out_z0);
}

// Round 11
// 643.057 us; speedup vs baseline: 1.0781x; 1.0781x over previous
//
#include <hip/hip_runtime.h>
#include <hip/hip_fp16.h>

#define F_IN 256
#define HID 128

typedef _Float16 half8 __attribute__((ext_vector_type(8)));
typedef _Float16 half4v __attribute__((ext_vector_type(4)));
typedef float f32x4 __attribute__((ext_vector_type(4)));
typedef unsigned int uint4v __attribute__((ext_vector_type(4)));

// ---------------- graph preprocessing (fused launches) ----------------

// blocks [0, nbE): edge counting for both graphs; blocks [nbE, nbE+96): W cvt.
__global__ void k_count_cvt(const int* __restrict__ col_s, int E, int* __restrict__ cnt_s,
                            const int* __restrict__ col_k, int EK, int* __restrict__ cnt_k,
                            int nbE,
                            const float* __restrict__ W0, const float* __restrict__ W1,
                            const float* __restrict__ W2, _Float16* __restrict__ Wh) {
  if ((int)blockIdx.x < nbE) {
    int e = blockIdx.x * 256 + threadIdx.x;
    if (e < E) {
      atomicAdd(&cnt_s[col_s[e]], 1);
    } else {
      int f = e - E;
      if (f < EK) atomicAdd(&cnt_k[col_k[f]], 1);
    }
  } else {
    const int sz = HID * F_IN;                    // 32768
    int idx = ((blockIdx.x - nbE) * 256 + threadIdx.x) * 4;  // [0, 3*sz)
    const float* src = (idx < sz) ? (W0 + idx)
                     : (idx < 2 * sz) ? (W1 + idx - sz)
                     : (W2 + idx - 2 * sz);
    float4 v = *(const float4*)src;
    half4v o;
    o[0] = (_Float16)v.x; o[1] = (_Float16)v.y; o[2] = (_Float16)v.z; o[3] = (_Float16)v.w;
    *(half4v*)(Wh + idx) = o;
  }
}

// blockIdx.y selects graph (0 = structural, 1 = knn)
__global__ void k_scan_block2(const int* __restrict__ in0, const int* __restrict__ in1,
                              int n, int* __restrict__ out0, int* __restrict__ out1,
                              int* __restrict__ bsum) {
  const int* in = blockIdx.y ? in1 : in0;
  int* out = blockIdx.y ? out1 : out0;
  int* bs = bsum + blockIdx.y * 512;
  __shared__ int s[1024];
  int tid = threadIdx.x;
  int i = blockIdx.x * 1024 + tid;
  int v = (i < n) ? in[i] : 0;
  s[tid] = v;
  __syncthreads();
  for (int off = 1; off < 1024; off <<= 1) {
    int t = (tid >= off) ? s[tid - off] : 0;
    __syncthreads();
    s[tid] += t;
    __syncthreads();
  }
  if (i < n) out[i] = s[tid] - v;          // exclusive
  if (tid == 1023) bs[blockIdx.x] = s[1023];
}

__global__ void k_scan_single2(int* __restrict__ bsum, int nb,
                               int* __restrict__ tail0, int* __restrict__ tail1) {
  if (threadIdx.x == 0 && blockIdx.x == 0) {
    int run = 0;
    for (int b = 0; b < nb; ++b) { int t = bsum[b]; bsum[b] = run; run += t; }
    *tail0 = run;
    run = 0;
    for (int b = 0; b < nb; ++b) { int t = bsum[512 + b]; bsum[512 + b] = run; run += t; }
    *tail1 = run;
  }
}

__global__ void k_add_off2(int* __restrict__ out0, int* __restrict__ out1,
                           const int* __restrict__ bsum, int n) {
  int* out = blockIdx.y ? out1 : out0;
  const int* bs = bsum + blockIdx.y * 512;
  int i = blockIdx.x * blockDim.x + threadIdx.x;
  if (i < n) out[i] += bs[i >> 10];
}

__global__ void k_scatter2(const int* __restrict__ row_s, const int* __restrict__ col_s, int E,
                           const int* __restrict__ offs_s, int* __restrict__ cur_s,
                           int* __restrict__ csr_s,
                           const int* __restrict__ row_k, const int* __restrict__ col_k, int EK,
                           const int* __restrict__ offs_k, int* __restrict__ cur_k,
                           int* __restrict__ csr_k) {
  int e = blockIdx.x * blockDim.x + threadIdx.x;
  if (e < E) {
    int c = col_s[e];
    int p = offs_s[c] + atomicAdd(&cur_s[c], 1);
    csr_s[p] = row_s[e];
  } else {
    int f = e - E;
    if (f < EK) {
      int c = col_k[f];
      int p = offs_k[c] + atomicAdd(&cur_k[c], 1);
      csr_k[p] = row_k[f];
    }
  }
}

// ---------------- fused MFMA GEMM, m97-style LDS double-buffered (round-8 form) ----------------

__device__ inline half8 cvt8(float4 a, float4 b) {
  half8 v;
  v[0] = (_Float16)a.x; v[1] = (_Float16)a.y; v[2] = (_Float16)a.z; v[3] = (_Float16)a.w;
  v[4] = (_Float16)b.x; v[5] = (_Float16)b.y; v[6] = (_Float16)b.z; v[7] = (_Float16)b.w;
  return v;
}

__global__ __launch_bounds__(256, 3) void k_gemm3(
    const float* __restrict__ x, const _Float16* __restrict__ Wh,
    const float* __restrict__ b0, const float* __restrict__ b1, const float* __restrict__ b2,
    int n, const int* __restrict__ cnt_s, const int* __restrict__ cnt_k,
    _Float16* __restrict__ gS1, _Float16* __restrict__ gS2,
    _Float16* __restrict__ gF2s, _Float16* __restrict__ gF2k)
{
  __shared__ __align__(16) char lds[49152];  // A0@0 A1@8192 B0@16384 B1@32768
  int tid = threadIdx.x;
  int m0 = blockIdx.x * 64;

  int rA = tid >> 2;
  int cA0 = (tid & 3) * 2, cA1 = cA0 + 1;
  int gnA = m0 + rA; if (gnA >= n) gnA = n - 1;
  const float* xA = x + (size_t)gnA * F_IN;
  unsigned aw0 = (unsigned)(rA * 128 + ((cA0 ^ (rA & 7)) << 4));
  unsigned aw1 = (unsigned)(rA * 128 + ((cA1 ^ (rA & 7)) << 4));
  int rB = tid >> 1;
  int cB0 = (tid & 1) * 4;
  unsigned bw[4];
#pragma unroll
  for (int i = 0; i < 4; ++i)
    bw[i] = (unsigned)(rB * 128 + (((cB0 + i) ^ (rB & 7)) << 4));

  int lane = tid & 63;
  int wv = tid >> 6;
  int wm = wv >> 1, wn = wv & 1;
  int l15 = lane & 15, lhi = lane >> 4;
  unsigned koff0 = (unsigned)(((0 * 4 + lhi) ^ (l15 & 7)) << 4);
  unsigned koff1 = (unsigned)(((1 * 4 + lhi) ^ (l15 & 7)) << 4);
  unsigned raw0 = (unsigned)((wm * 32 + 0 * 16 + l15) * 128);
  unsigned raw1 = (unsigned)((wm * 32 + 1 * 16 + l15) * 128);
  unsigned rbw[4];
#pragma unroll
  for (int ni = 0; ni < 4; ++ni)
    rbw[ni] = (unsigned)((wn * 64 + ni * 16 + l15) * 128);

  int nodebase = m0 + wm * 32 + l15;
  float ss[2], sk[2];
#pragma unroll
  for (int mi = 0; mi < 2; ++mi) {
    int nd = nodebase + mi * 16;
    int cn = (nd < n) ? nd : (n - 1);
    ss[mi] = rsqrtf((float)(cnt_s[cn] + 1));
    sk[mi] = rsqrtf((float)(cnt_k[cn] + 1));
  }

#pragma unroll 1
  for (int w = 0; w < 3; ++w) {
    const float* bias = (w == 0) ? b0 : (w == 1) ? b1 : b2;
    _Float16* dst = (w == 0) ? gS1 : (w == 1) ? gS2 : gF2s;
    const _Float16* WB = Wh + (size_t)w * (HID * F_IN) + (size_t)rB * F_IN;

    f32x4 acc[2][4];
#pragma unroll
    for (int ni = 0; ni < 4; ++ni) {
      float4 bv = *(const float4*)(bias + wn * 64 + ni * 16 + lhi * 4);
      f32x4 b4 = {bv.x, bv.y, bv.z, bv.w};
      acc[0][ni] = b4; acc[1][ni] = b4;
    }

    float4 fa[4]; uint4v ub[4];
    fa[0] = *(const float4*)(xA + 0 * 64 + cA0 * 8);
    fa[1] = *(const float4*)(xA + 0 * 64 + cA0 * 8 + 4);
    fa[2] = *(const float4*)(xA + 0 * 64 + cA1 * 8);
    fa[3] = *(const float4*)(xA + 0 * 64 + cA1 * 8 + 4);
#pragma unroll
    for (int i = 0; i < 4; ++i)
      ub[i] = *(const uint4v*)(WB + 0 * 64 + (cB0 + i) * 8);

#pragma unroll
    for (int kt = 0; kt < 4; ++kt) {
      char* Ab = lds + (kt & 1) * 8192;
      char* Bb = lds + 16384 + (kt & 1) * 16384;
      *(half8*)(Ab + aw0) = cvt8(fa[0], fa[1]);
      *(half8*)(Ab + aw1) = cvt8(fa[2], fa[3]);
#pragma unroll
      for (int i = 0; i < 4; ++i) *(uint4v*)(Bb + bw[i]) = ub[i];
      if (kt < 3) {
        fa[0] = *(const float4*)(xA + (kt + 1) * 64 + cA0 * 8);
        fa[1] = *(const float4*)(xA + (kt + 1) * 64 + cA0 * 8 + 4);
        fa[2] = *(const float4*)(xA + (kt + 1) * 64 + cA1 * 8);
        fa[3] = *(const float4*)(xA + (kt + 1) * 64 + cA1 * 8 + 4);
#pragma unroll
        for (int i = 0; i < 4; ++i)
          ub[i] = *(const uint4v*)(WB + (kt + 1) * 64 + (cB0 + i) * 8);
      }
      __syncthreads();
      {
        const char* Ar = Ab; const char* Br = Bb;
#pragma unroll
        for (int ks = 0; ks < 2; ++ks) {
          unsigned ko = ks ? koff1 : koff0;
          half8 xf0 = *(const half8*)(Ar + raw0 + ko);
          half8 xf1 = *(const half8*)(Ar + raw1 + ko);
          half8 wf0 = *(const half8*)(Br + rbw[0] + ko);
          half8 wf1 = *(const half8*)(Br + rbw[1] + ko);
          half8 wf2 = *(const half8*)(Br + rbw[2] + ko);
          half8 wf3 = *(const half8*)(Br + rbw[3] + ko);
          acc[0][0] = __builtin_amdgcn_mfma_f32_16x16x32_f16(wf0, xf0, acc[0][0], 0, 0, 0);
          acc[0][1] = __builtin_amdgcn_mfma_f32_16x16x32_f16(wf1, xf0, acc[0][1], 0, 0, 0);
          acc[0][2] = __builtin_amdgcn_mfma_f32_16x16x32_f16(wf2, xf0, acc[0][2], 0, 0, 0);
          acc[0][3] = __builtin_amdgcn_mfma_f32_16x16x32_f16(wf3, xf0, acc[0][3], 0, 0, 0);
          acc[1][0] = __builtin_amdgcn_mfma_f32_16x16x32_f16(wf0, xf1, acc[1][0], 0, 0, 0);
          acc[1][1] = __builtin_amdgcn_mfma_f32_16x16x32_f16(wf1, xf1, acc[1][1], 0, 0, 0);
          acc[1][2] = __builtin_amdgcn_mfma_f32_16x16x32_f16(wf2, xf1, acc[1][2], 0, 0, 0);
          acc[1][3] = __builtin_amdgcn_mfma_f32_16x16x32_f16(wf3, xf1, acc[1][3], 0, 0, 0);
        }
      }
    }

#pragma unroll
    for (int mi = 0; mi < 2; ++mi) {
      int nd = nodebase + mi * 16;
      if (nd < n) {
        size_t ob = (size_t)nd * HID + wn * 64 + lhi * 4;
        float s1 = ss[mi];
#pragma unroll
        for (int ni = 0; ni < 4; ++ni) {
          half4v o;
          o[0] = (_Float16)(acc[mi][ni][0] * s1); o[1] = (_Float16)(acc[mi][ni][1] * s1);
          o[2] = (_Float16)(acc[mi][ni][2] * s1); o[3] = (_Float16)(acc[mi][ni][3] * s1);
          *(half4v*)(dst + ob + ni * 16) = o;
        }
        if (w == 2) {
          float s2 = sk[mi];
#pragma unroll
          for (int ni = 0; ni < 4; ++ni) {
            half4v o2;
            o2[0] = (_Float16)(acc[mi][ni][0] * s2); o2[1] = (_Float16)(acc[mi][ni][1] * s2);
            o2[2] = (_Float16)(acc[mi][ni][2] * s2); o2[3] = (_Float16)(acc[mi][ni][3] * s2);
            *(half4v*)(gF2k + ob + ni * 16) = o2;
          }
        }
      }
    }
  }
}

// ---------------- SpMM (fp16 features, 16B/lane gathers, round-8 form) ----------------
// One wave per dest node. g = lane>>4 (edge slot), c = lane&15 (16B chunk).
// mode 0: *1/deg -> fp16; mode 1: *rsqrt(deg) -> fp32; mode 2: mode1 + addsrc.

__device__ inline float2 h2f2(unsigned int u) {
  __half2 h; *(unsigned int*)&h = u; return __half22float2(h);
}

__device__ __forceinline__ void spmm_body(
    const _Float16* gin, void* gout,
    const int* csr, const int* offs, const int* cnt,
    int n, int mode, const float* addsrc, int bid)
{
  int w = (bid << 2) | ((int)threadIdx.x >> 6);
  if (w >= n) return;
  int lane = threadIdx.x & 63;
  int g = lane >> 4;
  int c = lane & 15;
  int beg = offs[w], end = offs[w + 1];

  float acc[8];
#pragma unroll
  for (int i = 0; i < 8; ++i) acc[i] = 0.f;

  int e = beg;
#pragma unroll 1
  for (; e + 16 <= end; e += 16) {
    int idx[4];
#pragma unroll
    for (int j = 0; j < 4; ++j) idx[j] = csr[e + 4 * j + g];
    uint4v u[4];
#pragma unroll
    for (int j = 0; j < 4; ++j)
      u[j] = *(const uint4v*)(gin + ((size_t)(unsigned)idx[j] << 7) + c * 8);
#pragma unroll
    for (int j = 0; j < 4; ++j)
#pragma unroll
      for (int q = 0; q < 4; ++q) {
        float2 v = h2f2(u[j][q]);
        acc[q * 2] += v.x; acc[q * 2 + 1] += v.y;
      }
  }
#pragma unroll 1
  for (; e + 4 <= end; e += 4) {
    int idx = csr[e + g];
    uint4v u = *(const uint4v*)(gin + ((size_t)(unsigned)idx << 7) + c * 8);
#pragma unroll
    for (int q = 0; q < 4; ++q) {
      float2 v = h2f2(u[q]);
      acc[q * 2] += v.x; acc[q * 2 + 1] += v.y;
    }
  }
  {
    int rem = end - e;
    if (g < rem) {
      int idx = csr[e + g];
      uint4v u = *(const uint4v*)(gin + ((size_t)(unsigned)idx << 7) + c * 8);
#pragma unroll
      for (int q = 0; q < 4; ++q) {
        float2 v = h2f2(u[q]);
        acc[q * 2] += v.x; acc[q * 2 + 1] += v.y;
      }
    }
  }
  // reduce across the 4 g-groups
#pragma unroll
  for (int i = 0; i < 8; ++i) {
    acc[i] += __shfl_xor(acc[i], 16, 64);
    acc[i] += __shfl_xor(acc[i], 32, 64);
  }
  // self loop
  {
    uint4v u = *(const uint4v*)(gin + ((size_t)w << 7) + c * 8);
#pragma unroll
    for (int q = 0; q < 4; ++q) {
      float2 v = h2f2(u[q]);
      acc[q * 2] += v.x; acc[q * 2 + 1] += v.y;
    }
  }

  float deg = (float)(cnt[w] + 1);
  if (mode == 0) {
    float sc = 1.0f / deg;
    if (g == 0) {
      uint4v o;
#pragma unroll
      for (int q = 0; q < 4; ++q) {
        __half2 h = __float22half2_rn(make_float2(acc[q * 2] * sc, acc[q * 2 + 1] * sc));
        o[q] = *(unsigned int*)&h;
      }
      *(uint4v*)((_Float16*)gout + ((size_t)w << 7) + c * 8) = o;
    }
  } else {
    float sc = rsqrtf(deg);
    if (g == 0) {
      float o[8];
#pragma unroll
      for (int i = 0; i < 8; ++i) o[i] = acc[i] * sc;
      if (mode == 2) {
        const float* ap = addsrc + ((size_t)w << 7) + c * 8;
        float4 a0 = *(const float4*)ap;
        float4 a1 = *(const float4*)(ap + 4);
        o[0] += a0.x; o[1] += a0.y; o[2] += a0.z; o[3] += a0.w;
        o[4] += a1.x; o[5] += a1.y; o[6] += a1.z; o[7] += a1.w;
      }
      float* op = (float*)gout + ((size_t)w << 7) + c * 8;
      *(float4*)op = make_float4(o[0], o[1], o[2], o[3]);
      *(float4*)(op + 4) = make_float4(o[4], o[5], o[6], o[7]);
    }
  }
}

__global__ __launch_bounds__(256) void k_spmm_h(
    const _Float16* __restrict__ gin, void* __restrict__ gout,
    const int* __restrict__ csr, const int* __restrict__ offs, const int* __restrict__ cnt,
    int n, int mode, const float* __restrict__ addsrc)
{
  spmm_body(gin, gout, csr, offs, cnt, n, mode, addsrc, blockIdx.x);
}

// Fused dual-graph SpMM: blocks [0,nblkA) run pass A (structural s2 step),
// blocks [nblkA,..) run pass B (knn mode-2 step). The two passes are
// data-independent; fusing overlaps their memory streams (spmm_h alone runs
// at 2.6 TB/s < the 3.9 TB/s demonstrated fabric ceiling).
__global__ __launch_bounds__(256) void k_spmm_dual(
    const _Float16* ginA, void* goutA,
    const int* csrA, const int* offsA, const int* cntA, int modeA, const float* addA,
    const _Float16* ginB, void* goutB,
    const int* csrB, const int* offsB, const int* cntB, int modeB, const float* addB,
    int nblkA, int n)
{
  if ((int)blockIdx.x < nblkA) {
    spmm_body(ginA, goutA, csrA, offsA, cntA, n, modeA, addA, blockIdx.x);
  } else {
    spmm_body(ginB, goutB, csrB, offsB, cntB, n, modeB, addB, blockIdx.x - nblkA);
  }
}

// 3 feature matrices propagated in one pass over the graph (round-8 form)
__global__ __launch_bounds__(256) void k_spmm3(
    const _Float16* __restrict__ g0, const _Float16* __restrict__ g1,
    const _Float16* __restrict__ g2,
    void* __restrict__ o0, void* __restrict__ o1, void* __restrict__ o2,
    int md0, int md1, int md2,
    const int* __restrict__ csr, const int* __restrict__ offs, const int* __restrict__ cnt,
    int n)
{
  int w = (blockIdx.x << 2) | ((int)threadIdx.x >> 6);
  if (w >= n) return;
  int lane = threadIdx.x & 63;
  int g = lane >> 4;
  int c = lane & 15;
  int beg = offs[w], end = offs[w + 1];

  float a0[8], a1[8], a2[8];
#pragma unroll
  for (int i = 0; i < 8; ++i) { a0[i] = 0.f; a1[i] = 0.f; a2[i] = 0.f; }

  int e = beg;
#pragma unroll 1
  for (; e + 4 <= end; e += 4) {
    size_t off = ((size_t)(unsigned)csr[e + g] << 7) + c * 8;
    uint4v u0 = *(const uint4v*)(g0 + off);
    uint4v u1 = *(const uint4v*)(g1 + off);
    uint4v u2 = *(const uint4v*)(g2 + off);
#pragma unroll
    for (int q = 0; q < 4; ++q) {
      float2 v;
      v = h2f2(u0[q]); a0[q * 2] += v.x; a0[q * 2 + 1] += v.y;
      v = h2f2(u1[q]); a1[q * 2] += v.x; a1[q * 2 + 1] += v.y;
      v = h2f2(u2[q]); a2[q * 2] += v.x; a2[q * 2 + 1] += v.y;
    }
  }
  {
    int rem = end - e;
    if (g < rem) {
      size_t off = ((size_t)(unsigned)csr[e + g] << 7) + c * 8;
      uint4v u0 = *(const uint4v*)(g0 + off);
      uint4v u1 = *(const uint4v*)(g1 + off);
      uint4v u2 = *(const uint4v*)(g2 + off);
#pragma unroll
      for (int q = 0; q < 4; ++q) {
        float2 v;
        v = h2f2(u0[q]); a0[q * 2] += v.x; a0[q * 2 + 1] += v.y;
        v = h2f2(u1[q]); a1[q * 2] += v.x; a1[q * 2 + 1] += v.y;
        v = h2f2(u2[q]); a2[q * 2] += v.x; a2[q * 2 + 1] += v.y;
      }
    }
  }
#pragma unroll
  for (int i = 0; i < 8; ++i) {
    a0[i] += __shfl_xor(a0[i], 16, 64); a0[i] += __shfl_xor(a0[i], 32, 64);
    a1[i] += __shfl_xor(a1[i], 16, 64); a1[i] += __shfl_xor(a1[i], 32, 64);
    a2[i] += __shfl_xor(a2[i], 16, 64); a2[i] += __shfl_xor(a2[i], 32, 64);
  }
  // self loops
  {
    size_t off = ((size_t)w << 7) + c * 8;
    uint4v u0 = *(const uint4v*)(g0 + off);
    uint4v u1 = *(const uint4v*)(g1 + off);
    uint4v u2 = *(const uint4v*)(g2 + off);
#pragma unroll
    for (int q = 0; q < 4; ++q) {
      float2 v;
      v = h2f2(u0[q]); a0[q * 2] += v.x; a0[q * 2 + 1] += v.y;
      v = h2f2(u1[q]); a1[q * 2] += v.x; a1[q * 2 + 1] += v.y;
      v = h2f2(u2[q]); a2[q * 2] += v.x; a2[q * 2 + 1] += v.y;
    }
  }

  float deg = (float)(cnt[w] + 1);
  if (g == 0) {
    float inv = 1.0f / deg, rs = rsqrtf(deg);
    {
      float sc = (md0 == 0) ? inv : rs;
      if (md0 == 0) {
        uint4v o;
#pragma unroll
        for (int q = 0; q < 4; ++q) {
          __half2 h = __float22half2_rn(make_float2(a0[q * 2] * sc, a0[q * 2 + 1] * sc));
          o[q] = *(unsigned int*)&h;
        }
        *(uint4v*)((_Float16*)o0 + ((size_t)w << 7) + c * 8) = o;
      } else {
        float* op = (float*)o0 + ((size_t)w << 7) + c * 8;
        *(float4*)op = make_float4(a0[0] * sc, a0[1] * sc, a0[2] * sc, a0[3] * sc);
        *(float4*)(op + 4) = make_float4(a0[4] * sc, a0[5] * sc, a0[6] * sc, a0[7] * sc);
      }
    }
    {
      float sc = (md1 == 0) ? inv : rs;
      if (md1 == 0) {
        uint4v o;
#pragma unroll
        for (int q = 0; q < 4; ++q) {
          __half2 h = __float22half2_rn(make_float2(a1[q * 2] * sc, a1[q * 2 + 1] * sc));
          o[q] = *(unsigned int*)&h;
        }
        *(uint4v*)((_Float16*)o1 + ((size_t)w << 7) + c * 8) = o;
      } else {
        float* op = (float*)o1 + ((size_t)w << 7) + c * 8;
        *(float4*)op = make_float4(a1[0] * sc, a1[1] * sc, a1[2] * sc, a1[3] * sc);
        *(float4*)(op + 4) = make_float4(a1[4] * sc, a1[5] * sc, a1[6] * sc, a1[7] * sc);
      }
    }
    {
      float sc = (md2 == 0) ? inv : rs;
      if (md2 == 0) {
        uint4v o;
#pragma unroll
        for (int q = 0; q < 4; ++q) {
          __half2 h = __float22half2_rn(make_float2(a2[q * 2] * sc, a2[q * 2 + 1] * sc));
          o[q] = *(unsigned int*)&h;
        }
        *(uint4v*)((_Float16*)o2 + ((size_t)w << 7) + c * 8) = o;
      } else {
        float* op = (float*)o2 + ((size_t)w << 7) + c * 8;
        *(float4*)op = make_float4(a2[0] * sc, a2[1] * sc, a2[2] * sc, a2[3] * sc);
        *(float4*)(op + 4) = make_float4(a2[4] * sc, a2[5] * sc, a2[6] * sc, a2[7] * sc);
      }
    }
  }
}

// ---------------- launch ----------------

extern "C" void kernel_launch(void* const* d_in, const int* in_sizes, int n_in,
                              void* d_out, int out_size, void* d_ws, size_t ws_size,
                              hipStream_t stream) {
  const float* x    = (const float*)d_in[0];
  const int*   ei   = (const int*)d_in[1];
  const int*   knn  = (const int*)d_in[2];
  const float* W_s1 = (const float*)d_in[3];
  const float* b_s1 = (const float*)d_in[4];
  const float* W_s2 = (const float*)d_in[5];
  const float* b_s2 = (const float*)d_in[6];
  const float* W_f2 = (const float*)d_in[7];
  const float* b_f2 = (const float*)d_in[8];

  const int N  = in_sizes[0] / F_IN;
  const int E  = in_sizes[1] / 2;
  const int EK = in_sizes[2] / 2;
  const int* row_s = ei;   const int* col_s = ei + E;
  const int* row_k = knn;  const int* col_k = knn + EK;

  char* p = (char*)d_ws;
  auto carve = [&](size_t bytes) {
    char* r = p; p += (bytes + 511) & ~(size_t)511; return (void*)r;
  };
  int* cnt_s = (int*)carve((size_t)N * 4);
  int* cnt_k = (int*)carve((size_t)N * 4);
  int* cur_s = (int*)carve((size_t)N * 4);
  int* cur_k = (int*)carve((size_t)N * 4);
  char* zero_end = p;
  int* offs_s = (int*)carve((size_t)(N + 1) * 4);
  int* offs_k = (int*)carve((size_t)(N + 1) * 4);
  int* bsum   = (int*)carve(4096);
  int* csr_s  = (int*)carve((size_t)E * 4);
  int* csr_k  = (int*)carve((size_t)EK * 4);
  _Float16* Wh  = (_Float16*)carve((size_t)3 * HID * F_IN * 2);
  _Float16* gS1 = (_Float16*)carve((size_t)N * HID * 2);
  _Float16* gS2 = (_Float16*)carve((size_t)N * HID * 2);
  _Float16* gF2s= (_Float16*)carve((size_t)N * HID * 2);
  _Float16* gF2k= (_Float16*)carve((size_t)N * HID * 2);
  _Float16* tS2 = (_Float16*)carve((size_t)N * HID * 2);

  float* out_h0 = (float*)d_out;
  float* out_h1 = out_h0 + (size_t)N * HID;
  float* out_z0 = out_h1 + (size_t)N * HID;
  float* out_z1 = out_z0 + (size_t)N * HID;
  // z1 region (fp32, N*HID floats = 2x fp16 buffers) is free until the dual
  // launch -> scratch for the two single-use step-1 outputs.
  _Float16* tS1 = (_Float16*)out_z1;
  _Float16* tF2 = tS1 + (size_t)N * HID;

  hipMemsetAsync(d_ws, 0, (size_t)(zero_end - (char*)d_ws), stream);

  const int tpb = 256;
  int etot = E + EK;
  int nbE = (etot + tpb - 1) / tpb;
  k_count_cvt<<<nbE + 96, tpb, 0, stream>>>(col_s, E, cnt_s, col_k, EK, cnt_k, nbE,
                                            W_s1, W_s2, W_f2, Wh);

  int nb = (N + 1023) / 1024;
  dim3 sg(nb, 2);
  k_scan_block2<<<sg, 1024, 0, stream>>>(cnt_s, cnt_k, N, offs_s, offs_k, bsum);
  k_scan_single2<<<1, 64, 0, stream>>>(bsum, nb, offs_s + N, offs_k + N);
  dim3 ag((N + tpb - 1) / tpb, 2);
  k_add_off2<<<ag, tpb, 0, stream>>>(offs_s, offs_k, bsum, N);

  k_scatter2<<<nbE, tpb, 0, stream>>>(
      row_s, col_s, E, offs_s, cur_s, csr_s,
      row_k, col_k, EK, offs_k, cur_k, csr_k);

  k_gemm3<<<(N + 63) / 64, 256, 0, stream>>>(x, Wh, b_s1, b_s2, b_f2, N, cnt_s, cnt_k,
                                             gS1, gS2, gF2s, gF2k);

  int spmm_grid = (N + 3) / 4;

  // step 1 (all chains), step 2 (s1 & f2 finalize, s2 continues)
  k_spmm3<<<spmm_grid, 256, 0, stream>>>(gS1, gS2, gF2s,
                                         tS1, tS2, tF2, 0, 0, 0,
                                         csr_s, offs_s, cnt_s, N);
  k_spmm3<<<spmm_grid, 256, 0, stream>>>(tS1, tS2, tF2,
                                         out_h0, gS1, out_z0, 1, 0, 1,
                                         csr_s, offs_s, cnt_s, N);

  // s2 step 3 fused with the knn step (independent work, overlapped)
  k_spmm_dual<<<spmm_grid * 2, 256, 0, stream>>>(
      gS1, tS2, csr_s, offs_s, cnt_s, 0, nullptr,
      gF2k, out_z1, csr_k, offs_k, cnt_k, 2, out_z0,
      spmm_grid, N);

  // s2 steps 4..10: ping-pong tS2 <-> gS1
  {
    _Float16* cur = tS2; _Float16* alt = gS1;
    for (int it = 0; it < 6; ++it) {
      k_spmm_h<<<spmm_grid, 256, 0, stream>>>(cur, alt,
                                              csr_s, offs_s, cnt_s, N, 0, nullptr);
      _Float16* t = cur; cur = alt; alt = t;
    }
    k_spmm_h<<<spmm_grid, 256, 0, stream>>>(cur, out_h1,
                                            csr_s, offs_s, cnt_s, N, 1, nullptr);
  }
}

// Round 12
// 625.641 us; speedup vs baseline: 1.1081x; 1.0278x over previous
//
#include <hip/hip_runtime.h>
#include <hip/hip_fp16.h>

#define F_IN 256
#define HID 128

typedef _Float16 half8 __attribute__((ext_vector_type(8)));
typedef _Float16 half4v __attribute__((ext_vector_type(4)));
typedef float f32x4 __attribute__((ext_vector_type(4)));
typedef unsigned int uint4v __attribute__((ext_vector_type(4)));

// ---------------- graph preprocessing (fused launches) ----------------

// blocks [0, nbE): edge counting for both graphs; blocks [nbE, nbE+96): W cvt.
__global__ void k_count_cvt(const int* __restrict__ col_s, int E, int* __restrict__ cnt_s,
                            const int* __restrict__ col_k, int EK, int* __restrict__ cnt_k,
                            int nbE,
                            const float* __restrict__ W0, const float* __restrict__ W1,
                            const float* __restrict__ W2, _Float16* __restrict__ Wh) {
  if ((int)blockIdx.x < nbE) {
    int e = blockIdx.x * 256 + threadIdx.x;
    if (e < E) {
      atomicAdd(&cnt_s[col_s[e]], 1);
    } else {
      int f = e - E;
      if (f < EK) atomicAdd(&cnt_k[col_k[f]], 1);
    }
  } else {
    const int sz = HID * F_IN;                    // 32768
    int idx = ((blockIdx.x - nbE) * 256 + threadIdx.x) * 4;  // [0, 3*sz)
    const float* src = (idx < sz) ? (W0 + idx)
                     : (idx < 2 * sz) ? (W1 + idx - sz)
                     : (W2 + idx - 2 * sz);
    float4 v = *(const float4*)src;
    half4v o;
    o[0] = (_Float16)v.x; o[1] = (_Float16)v.y; o[2] = (_Float16)v.z; o[3] = (_Float16)v.w;
    *(half4v*)(Wh + idx) = o;
  }
}

// blockIdx.y selects graph (0 = structural, 1 = knn)
__global__ void k_scan_block2(const int* __restrict__ in0, const int* __restrict__ in1,
                              int n, int* __restrict__ out0, int* __restrict__ out1,
                              int* __restrict__ bsum) {
  const int* in = blockIdx.y ? in1 : in0;
  int* out = blockIdx.y ? out1 : out0;
  int* bs = bsum + blockIdx.y * 512;
  __shared__ int s[1024];
  int tid = threadIdx.x;
  int i = blockIdx.x * 1024 + tid;
  int v = (i < n) ? in[i] : 0;
  s[tid] = v;
  __syncthreads();
  for (int off = 1; off < 1024; off <<= 1) {
    int t = (tid >= off) ? s[tid - off] : 0;
    __syncthreads();
    s[tid] += t;
    __syncthreads();
  }
  if (i < n) out[i] = s[tid] - v;          // exclusive
  if (tid == 1023) bs[blockIdx.x] = s[1023];
}

__global__ void k_scan_single2(int* __restrict__ bsum, int nb,
                               int* __restrict__ tail0, int* __restrict__ tail1) {
  if (threadIdx.x == 0 && blockIdx.x == 0) {
    int run = 0;
    for (int b = 0; b < nb; ++b) { int t = bsum[b]; bsum[b] = run; run += t; }
    *tail0 = run;
    run = 0;
    for (int b = 0; b < nb; ++b) { int t = bsum[512 + b]; bsum[512 + b] = run; run += t; }
    *tail1 = run;
  }
}

__global__ void k_add_off2(int* __restrict__ out0, int* __restrict__ out1,
                           const int* __restrict__ bsum, int n) {
  int* out = blockIdx.y ? out1 : out0;
  const int* bs = bsum + blockIdx.y * 512;
  int i = blockIdx.x * blockDim.x + threadIdx.x;
  if (i < n) out[i] += bs[i >> 10];
}

// ---------------- fused MFMA GEMM + CSR scatter (independent work, overlapped) ----------------
// blocks [0, nbG): m97-style LDS double-buffered GEMM (round-8 form, unchanged);
// blocks [nbG, ...): CSR scatter for both graphs (pure atomics, backfills CUs).

__device__ inline half8 cvt8(float4 a, float4 b) {
  half8 v;
  v[0] = (_Float16)a.x; v[1] = (_Float16)a.y; v[2] = (_Float16)a.z; v[3] = (_Float16)a.w;
  v[4] = (_Float16)b.x; v[5] = (_Float16)b.y; v[6] = (_Float16)b.z; v[7] = (_Float16)b.w;
  return v;
}

__global__ __launch_bounds__(256, 3) void k_gemm3_scatter(
    const float* __restrict__ x, const _Float16* __restrict__ Wh,
    const float* __restrict__ b0, const float* __restrict__ b1, const float* __restrict__ b2,
    int n, const int* __restrict__ cnt_s, const int* __restrict__ cnt_k,
    _Float16* __restrict__ gS1, _Float16* __restrict__ gS2,
    _Float16* __restrict__ gF2s, _Float16* __restrict__ gF2k,
    const int* __restrict__ row_s, const int* __restrict__ col_s, int E,
    const int* __restrict__ offs_s, int* __restrict__ cur_s, int* __restrict__ csr_s,
    const int* __restrict__ row_k, const int* __restrict__ col_k, int EK,
    const int* __restrict__ offs_k, int* __restrict__ cur_k, int* __restrict__ csr_k,
    int nbG)
{
  __shared__ __align__(16) char lds[49152];  // A0@0 A1@8192 B0@16384 B1@32768
  int tid = threadIdx.x;

  if ((int)blockIdx.x >= nbG) {
    // -------- scatter tail blocks --------
    int e = (blockIdx.x - nbG) * 256 + tid;
    if (e < E) {
      int c = col_s[e];
      int p = offs_s[c] + atomicAdd(&cur_s[c], 1);
      csr_s[p] = row_s[e];
    } else {
      int f = e - E;
      if (f < EK) {
        int c = col_k[f];
        int p = offs_k[c] + atomicAdd(&cur_k[c], 1);
        csr_k[p] = row_k[f];
      }
    }
    return;
  }

  // -------- GEMM blocks --------
  int m0 = blockIdx.x * 64;

  int rA = tid >> 2;
  int cA0 = (tid & 3) * 2, cA1 = cA0 + 1;
  int gnA = m0 + rA; if (gnA >= n) gnA = n - 1;
  const float* xA = x + (size_t)gnA * F_IN;
  unsigned aw0 = (unsigned)(rA * 128 + ((cA0 ^ (rA & 7)) << 4));
  unsigned aw1 = (unsigned)(rA * 128 + ((cA1 ^ (rA & 7)) << 4));
  int rB = tid >> 1;
  int cB0 = (tid & 1) * 4;
  unsigned bw[4];
#pragma unroll
  for (int i = 0; i < 4; ++i)
    bw[i] = (unsigned)(rB * 128 + (((cB0 + i) ^ (rB & 7)) << 4));

  int lane = tid & 63;
  int wv = tid >> 6;
  int wm = wv >> 1, wn = wv & 1;
  int l15 = lane & 15, lhi = lane >> 4;
  unsigned koff0 = (unsigned)(((0 * 4 + lhi) ^ (l15 & 7)) << 4);
  unsigned koff1 = (unsigned)(((1 * 4 + lhi) ^ (l15 & 7)) << 4);
  unsigned raw0 = (unsigned)((wm * 32 + 0 * 16 + l15) * 128);
  unsigned raw1 = (unsigned)((wm * 32 + 1 * 16 + l15) * 128);
  unsigned rbw[4];
#pragma unroll
  for (int ni = 0; ni < 4; ++ni)
    rbw[ni] = (unsigned)((wn * 64 + ni * 16 + l15) * 128);

  int nodebase = m0 + wm * 32 + l15;
  float ss[2], sk[2];
#pragma unroll
  for (int mi = 0; mi < 2; ++mi) {
    int nd = nodebase + mi * 16;
    int cn = (nd < n) ? nd : (n - 1);
    ss[mi] = rsqrtf((float)(cnt_s[cn] + 1));
    sk[mi] = rsqrtf((float)(cnt_k[cn] + 1));
  }

#pragma unroll 1
  for (int w = 0; w < 3; ++w) {
    const float* bias = (w == 0) ? b0 : (w == 1) ? b1 : b2;
    _Float16* dst = (w == 0) ? gS1 : (w == 1) ? gS2 : gF2s;
    const _Float16* WB = Wh + (size_t)w * (HID * F_IN) + (size_t)rB * F_IN;

    f32x4 acc[2][4];
#pragma unroll
    for (int ni = 0; ni < 4; ++ni) {
      float4 bv = *(const float4*)(bias + wn * 64 + ni * 16 + lhi * 4);
      f32x4 b4 = {bv.x, bv.y, bv.z, bv.w};
      acc[0][ni] = b4; acc[1][ni] = b4;
    }

    float4 fa[4]; uint4v ub[4];
    fa[0] = *(const float4*)(xA + 0 * 64 + cA0 * 8);
    fa[1] = *(const float4*)(xA + 0 * 64 + cA0 * 8 + 4);
    fa[2] = *(const float4*)(xA + 0 * 64 + cA1 * 8);
    fa[3] = *(const float4*)(xA + 0 * 64 + cA1 * 8 + 4);
#pragma unroll
    for (int i = 0; i < 4; ++i)
      ub[i] = *(const uint4v*)(WB + 0 * 64 + (cB0 + i) * 8);

#pragma unroll
    for (int kt = 0; kt < 4; ++kt) {
      char* Ab = lds + (kt & 1) * 8192;
      char* Bb = lds + 16384 + (kt & 1) * 16384;
      *(half8*)(Ab + aw0) = cvt8(fa[0], fa[1]);
      *(half8*)(Ab + aw1) = cvt8(fa[2], fa[3]);
#pragma unroll
      for (int i = 0; i < 4; ++i) *(uint4v*)(Bb + bw[i]) = ub[i];
      if (kt < 3) {
        fa[0] = *(const float4*)(xA + (kt + 1) * 64 + cA0 * 8);
        fa[1] = *(const float4*)(xA + (kt + 1) * 64 + cA0 * 8 + 4);
        fa[2] = *(const float4*)(xA + (kt + 1) * 64 + cA1 * 8);
        fa[3] = *(const float4*)(xA + (kt + 1) * 64 + cA1 * 8 + 4);
#pragma unroll
        for (int i = 0; i < 4; ++i)
          ub[i] = *(const uint4v*)(WB + (kt + 1) * 64 + (cB0 + i) * 8);
      }
      __syncthreads();
      {
        const char* Ar = Ab; const char* Br = Bb;
#pragma unroll
        for (int ks = 0; ks < 2; ++ks) {
          unsigned ko = ks ? koff1 : koff0;
          half8 xf0 = *(const half8*)(Ar + raw0 + ko);
          half8 xf1 = *(const half8*)(Ar + raw1 + ko);
          half8 wf0 = *(const half8*)(Br + rbw[0] + ko);
          half8 wf1 = *(const half8*)(Br + rbw[1] + ko);
          half8 wf2 = *(const half8*)(Br + rbw[2] + ko);
          half8 wf3 = *(const half8*)(Br + rbw[3] + ko);
          acc[0][0] = __builtin_amdgcn_mfma_f32_16x16x32_f16(wf0, xf0, acc[0][0], 0, 0, 0);
          acc[0][1] = __builtin_amdgcn_mfma_f32_16x16x32_f16(wf1, xf0, acc[0][1], 0, 0, 0);
          acc[0][2] = __builtin_amdgcn_mfma_f32_16x16x32_f16(wf2, xf0, acc[0][2], 0, 0, 0);
          acc[0][3] = __builtin_amdgcn_mfma_f32_16x16x32_f16(wf3, xf0, acc[0][3], 0, 0, 0);
          acc[1][0] = __builtin_amdgcn_mfma_f32_16x16x32_f16(wf0, xf1, acc[1][0], 0, 0, 0);
          acc[1][1] = __builtin_amdgcn_mfma_f32_16x16x32_f16(wf1, xf1, acc[1][1], 0, 0, 0);
          acc[1][2] = __builtin_amdgcn_mfma_f32_16x16x32_f16(wf2, xf1, acc[1][2], 0, 0, 0);
          acc[1][3] = __builtin_amdgcn_mfma_f32_16x16x32_f16(wf3, xf1, acc[1][3], 0, 0, 0);
        }
      }
    }

#pragma unroll
    for (int mi = 0; mi < 2; ++mi) {
      int nd = nodebase + mi * 16;
      if (nd < n) {
        size_t ob = (size_t)nd * HID + wn * 64 + lhi * 4;
        float s1 = ss[mi];
#pragma unroll
        for (int ni = 0; ni < 4; ++ni) {
          half4v o;
          o[0] = (_Float16)(acc[mi][ni][0] * s1); o[1] = (_Float16)(acc[mi][ni][1] * s1);
          o[2] = (_Float16)(acc[mi][ni][2] * s1); o[3] = (_Float16)(acc[mi][ni][3] * s1);
          *(half4v*)(dst + ob + ni * 16) = o;
        }
        if (w == 2) {
          float s2 = sk[mi];
#pragma unroll
          for (int ni = 0; ni < 4; ++ni) {
            half4v o2;
            o2[0] = (_Float16)(acc[mi][ni][0] * s2); o2[1] = (_Float16)(acc[mi][ni][1] * s2);
            o2[2] = (_Float16)(acc[mi][ni][2] * s2); o2[3] = (_Float16)(acc[mi][ni][3] * s2);
            *(half4v*)(gF2k + ob + ni * 16) = o2;
          }
        }
      }
    }
  }
}

// ---------------- SpMM (fp16 features, 16B/lane gathers, round-8 form) ----------------
// One wave per dest node. g = lane>>4 (edge slot), c = lane&15 (16B chunk).
// mode 0: *1/deg -> fp16; mode 1: *rsqrt(deg) -> fp32; mode 2: mode1 + addsrc.

__device__ inline float2 h2f2(unsigned int u) {
  __half2 h; *(unsigned int*)&h = u; return __half22float2(h);
}

__device__ __forceinline__ void spmm_body(
    const _Float16* gin, void* gout,
    const int* csr, const int* offs, const int* cnt,
    int n, int mode, const float* addsrc, int bid)
{
  int w = (bid << 2) | ((int)threadIdx.x >> 6);
  if (w >= n) return;
  int lane = threadIdx.x & 63;
  int g = lane >> 4;
  int c = lane & 15;
  int beg = offs[w], end = offs[w + 1];

  float acc[8];
#pragma unroll
  for (int i = 0; i < 8; ++i) acc[i] = 0.f;

  int e = beg;
#pragma unroll 1
  for (; e + 16 <= end; e += 16) {
    int idx[4];
#pragma unroll
    for (int j = 0; j < 4; ++j) idx[j] = csr[e + 4 * j + g];
    uint4v u[4];
#pragma unroll
    for (int j = 0; j < 4; ++j)
      u[j] = *(const uint4v*)(gin + ((size_t)(unsigned)idx[j] << 7) + c * 8);
#pragma unroll
    for (int j = 0; j < 4; ++j)
#pragma unroll
      for (int q = 0; q < 4; ++q) {
        float2 v = h2f2(u[j][q]);
        acc[q * 2] += v.x; acc[q * 2 + 1] += v.y;
      }
  }
#pragma unroll 1
  for (; e + 4 <= end; e += 4) {
    int idx = csr[e + g];
    uint4v u = *(const uint4v*)(gin + ((size_t)(unsigned)idx << 7) + c * 8);
#pragma unroll
    for (int q = 0; q < 4; ++q) {
      float2 v = h2f2(u[q]);
      acc[q * 2] += v.x; acc[q * 2 + 1] += v.y;
    }
  }
  {
    int rem = end - e;
    if (g < rem) {
      int idx = csr[e + g];
      uint4v u = *(const uint4v*)(gin + ((size_t)(unsigned)idx << 7) + c * 8);
#pragma unroll
      for (int q = 0; q < 4; ++q) {
        float2 v = h2f2(u[q]);
        acc[q * 2] += v.x; acc[q * 2 + 1] += v.y;
      }
    }
  }
  // reduce across the 4 g-groups
#pragma unroll
  for (int i = 0; i < 8; ++i) {
    acc[i] += __shfl_xor(acc[i], 16, 64);
    acc[i] += __shfl_xor(acc[i], 32, 64);
  }
  // self loop
  {
    uint4v u = *(const uint4v*)(gin + ((size_t)w << 7) + c * 8);
#pragma unroll
    for (int q = 0; q < 4; ++q) {
      float2 v = h2f2(u[q]);
      acc[q * 2] += v.x; acc[q * 2 + 1] += v.y;
    }
  }

  float deg = (float)(cnt[w] + 1);
  if (mode == 0) {
    float sc = 1.0f / deg;
    if (g == 0) {
      uint4v o;
#pragma unroll
      for (int q = 0; q < 4; ++q) {
        __half2 h = __float22half2_rn(make_float2(acc[q * 2] * sc, acc[q * 2 + 1] * sc));
        o[q] = *(unsigned int*)&h;
      }
      *(uint4v*)((_Float16*)gout + ((size_t)w << 7) + c * 8) = o;
    }
  } else {
    float sc = rsqrtf(deg);
    if (g == 0) {
      float o[8];
#pragma unroll
      for (int i = 0; i < 8; ++i) o[i] = acc[i] * sc;
      if (mode == 2) {
        const float* ap = addsrc + ((size_t)w << 7) + c * 8;
        float4 a0 = *(const float4*)ap;
        float4 a1 = *(const float4*)(ap + 4);
        o[0] += a0.x; o[1] += a0.y; o[2] += a0.z; o[3] += a0.w;
        o[4] += a1.x; o[5] += a1.y; o[6] += a1.z; o[7] += a1.w;
      }
      float* op = (float*)gout + ((size_t)w << 7) + c * 8;
      *(float4*)op = make_float4(o[0], o[1], o[2], o[3]);
      *(float4*)(op + 4) = make_float4(o[4], o[5], o[6], o[7]);
    }
  }
}

__global__ __launch_bounds__(256) void k_spmm_h(
    const _Float16* __restrict__ gin, void* __restrict__ gout,
    const int* __restrict__ csr, const int* __restrict__ offs, const int* __restrict__ cnt,
    int n, int mode, const float* __restrict__ addsrc)
{
  spmm_body(gin, gout, csr, offs, cnt, n, mode, addsrc, blockIdx.x);
}

// Fused dual-graph SpMM: blocks [0,nblkA) run pass A (structural s2 step),
// blocks [nblkA,..) run pass B (knn mode-2 step).
__global__ __launch_bounds__(256) void k_spmm_dual(
    const _Float16* ginA, void* goutA,
    const int* csrA, const int* offsA, const int* cntA, int modeA, const float* addA,
    const _Float16* ginB, void* goutB,
    const int* csrB, const int* offsB, const int* cntB, int modeB, const float* addB,
    int nblkA, int n)
{
  if ((int)blockIdx.x < nblkA) {
    spmm_body(ginA, goutA, csrA, offsA, cntA, n, modeA, addA, blockIdx.x);
  } else {
    spmm_body(ginB, goutB, csrB, offsB, cntB, n, modeB, addB, blockIdx.x - nblkA);
  }
}

// 3 feature matrices propagated in one pass over the graph (round-8 form)
__global__ __launch_bounds__(256) void k_spmm3(
    const _Float16* __restrict__ g0, const _Float16* __restrict__ g1,
    const _Float16* __restrict__ g2,
    void* __restrict__ o0, void* __restrict__ o1, void* __restrict__ o2,
    int md0, int md1, int md2,
    const int* __restrict__ csr, const int* __restrict__ offs, const int* __restrict__ cnt,
    int n)
{
  int w = (blockIdx.x << 2) | ((int)threadIdx.x >> 6);
  if (w >= n) return;
  int lane = threadIdx.x & 63;
  int g = lane >> 4;
  int c = lane & 15;
  int beg = offs[w], end = offs[w + 1];

  float a0[8], a1[8], a2[8];
#pragma unroll
  for (int i = 0; i < 8; ++i) { a0[i] = 0.f; a1[i] = 0.f; a2[i] = 0.f; }

  int e = beg;
#pragma unroll 1
  for (; e + 4 <= end; e += 4) {
    size_t off = ((size_t)(unsigned)csr[e + g] << 7) + c * 8;
    uint4v u0 = *(const uint4v*)(g0 + off);
    uint4v u1 = *(const uint4v*)(g1 + off);
    uint4v u2 = *(const uint4v*)(g2 + off);
#pragma unroll
    for (int q = 0; q < 4; ++q) {
      float2 v;
      v = h2f2(u0[q]); a0[q * 2] += v.x; a0[q * 2 + 1] += v.y;
      v = h2f2(u1[q]); a1[q * 2] += v.x; a1[q * 2 + 1] += v.y;
      v = h2f2(u2[q]); a2[q * 2] += v.x; a2[q * 2 + 1] += v.y;
    }
  }
  {
    int rem = end - e;
    if (g < rem) {
      size_t off = ((size_t)(unsigned)csr[e + g] << 7) + c * 8;
      uint4v u0 = *(const uint4v*)(g0 + off);
      uint4v u1 = *(const uint4v*)(g1 + off);
      uint4v u2 = *(const uint4v*)(g2 + off);
#pragma unroll
      for (int q = 0; q < 4; ++q) {
        float2 v;
        v = h2f2(u0[q]); a0[q * 2] += v.x; a0[q * 2 + 1] += v.y;
        v = h2f2(u1[q]); a1[q * 2] += v.x; a1[q * 2 + 1] += v.y;
        v = h2f2(u2[q]); a2[q * 2] += v.x; a2[q * 2 + 1] += v.y;
      }
    }
  }
#pragma unroll
  for (int i = 0; i < 8; ++i) {
    a0[i] += __shfl_xor(a0[i], 16, 64); a0[i] += __shfl_xor(a0[i], 32, 64);
    a1[i] += __shfl_xor(a1[i], 16, 64); a1[i] += __shfl_xor(a1[i], 32, 64);
    a2[i] += __shfl_xor(a2[i], 16, 64); a2[i] += __shfl_xor(a2[i], 32, 64);
  }
  // self loops
  {
    size_t off = ((size_t)w << 7) + c * 8;
    uint4v u0 = *(const uint4v*)(g0 + off);
    uint4v u1 = *(const uint4v*)(g1 + off);
    uint4v u2 = *(const uint4v*)(g2 + off);
#pragma unroll
    for (int q = 0; q < 4; ++q) {
      float2 v;
      v = h2f2(u0[q]); a0[q * 2] += v.x; a0[q * 2 + 1] += v.y;
      v = h2f2(u1[q]); a1[q * 2] += v.x; a1[q * 2 + 1] += v.y;
      v = h2f2(u2[q]); a2[q * 2] += v.x; a2[q * 2 + 1] += v.y;
    }
  }

  float deg = (float)(cnt[w] + 1);
  if (g == 0) {
    float inv = 1.0f / deg, rs = rsqrtf(deg);
    {
      float sc = (md0 == 0) ? inv : rs;
      if (md0 == 0) {
        uint4v o;
#pragma unroll
        for (int q = 0; q < 4; ++q) {
          __half2 h = __float22half2_rn(make_float2(a0[q * 2] * sc, a0[q * 2 + 1] * sc));
          o[q] = *(unsigned int*)&h;
        }
        *(uint4v*)((_Float16*)o0 + ((size_t)w << 7) + c * 8) = o;
      } else {
        float* op = (float*)o0 + ((size_t)w << 7) + c * 8;
        *(float4*)op = make_float4(a0[0] * sc, a0[1] * sc, a0[2] * sc, a0[3] * sc);
        *(float4*)(op + 4) = make_float4(a0[4] * sc, a0[5] * sc, a0[6] * sc, a0[7] * sc);
      }
    }
    {
      float sc = (md1 == 0) ? inv : rs;
      if (md1 == 0) {
        uint4v o;
#pragma unroll
        for (int q = 0; q < 4; ++q) {
          __half2 h = __float22half2_rn(make_float2(a1[q * 2] * sc, a1[q * 2 + 1] * sc));
          o[q] = *(unsigned int*)&h;
        }
        *(uint4v*)((_Float16*)o1 + ((size_t)w << 7) + c * 8) = o;
      } else {
        float* op = (float*)o1 + ((size_t)w << 7) + c * 8;
        *(float4*)op = make_float4(a1[0] * sc, a1[1] * sc, a1[2] * sc, a1[3] * sc);
        *(float4*)(op + 4) = make_float4(a1[4] * sc, a1[5] * sc, a1[6] * sc, a1[7] * sc);
      }
    }
    {
      float sc = (md2 == 0) ? inv : rs;
      if (md2 == 0) {
        uint4v o;
#pragma unroll
        for (int q = 0; q < 4; ++q) {
          __half2 h = __float22half2_rn(make_float2(a2[q * 2] * sc, a2[q * 2 + 1] * sc));
          o[q] = *(unsigned int*)&h;
        }
        *(uint4v*)((_Float16*)o2 + ((size_t)w << 7) + c * 8) = o;
      } else {
        float* op = (float*)o2 + ((size_t)w << 7) + c * 8;
        *(float4*)op = make_float4(a2[0] * sc, a2[1] * sc, a2[2] * sc, a2[3] * sc);
        *(float4*)(op + 4) = make_float4(a2[4] * sc, a2[5] * sc, a2[6] * sc, a2[7] * sc);
      }
    }
  }
}

// ---------------- launch ----------------

extern "C" void kernel_launch(void* const* d_in, const int* in_sizes, int n_in,
                              void* d_out, int out_size, void* d_ws, size_t ws_size,
                              hipStream_t stream) {
  const float* x    = (const float*)d_in[0];
  const int*   ei   = (const int*)d_in[1];
  const int*   knn  = (const int*)d_in[2];
  const float* W_s1 = (const float*)d_in[3];
  const float* b_s1 = (const float*)d_in[4];
  const float* W_s2 = (const float*)d_in[5];
  const float* b_s2 = (const float*)d_in[6];
  const float* W_f2 = (const float*)d_in[7];
  const float* b_f2 = (const float*)d_in[8];

  const int N  = in_sizes[0] / F_IN;
  const int E  = in_sizes[1] / 2;
  const int EK = in_sizes[2] / 2;
  const int* row_s = ei;   const int* col_s = ei + E;
  const int* row_k = knn;  const int* col_k = knn + EK;

  char* p = (char*)d_ws;
  auto carve = [&](size_t bytes) {
    char* r = p; p += (bytes + 511) & ~(size_t)511; return (void*)r;
  };
  int* cnt_s = (int*)carve((size_t)N * 4);
  int* cnt_k = (int*)carve((size_t)N * 4);
  int* cur_s = (int*)carve((size_t)N * 4);
  int* cur_k = (int*)carve((size_t)N * 4);
  char* zero_end = p;
  int* offs_s = (int*)carve((size_t)(N + 1) * 4);
  int* offs_k = (int*)carve((size_t)(N + 1) * 4);
  int* bsum   = (int*)carve(4096);
  int* csr_s  = (int*)carve((size_t)E * 4);
  int* csr_k  = (int*)carve((size_t)EK * 4);
  _Float16* Wh  = (_Float16*)carve((size_t)3 * HID * F_IN * 2);
  _Float16* gS1 = (_Float16*)carve((size_t)N * HID * 2);
  _Float16* gS2 = (_Float16*)carve((size_t)N * HID * 2);
  _Float16* gF2s= (_Float16*)carve((size_t)N * HID * 2);
  _Float16* gF2k= (_Float16*)carve((size_t)N * HID * 2);
  _Float16* tS2 = (_Float16*)carve((size_t)N * HID * 2);

  float* out_h0 = (float*)d_out;
  float* out_h1 = out_h0 + (size_t)N * HID;
  float* out_z0 = out_h1 + (size_t)N * HID;
  float* out_z1 = out_z0 + (size_t)N * HID;
  // z1 region (fp32, N*HID floats = 2x fp16 buffers) is free until the dual
  // launch -> scratch for the two single-use step-1 outputs.
  _Float16* tS1 = (_Float16*)out_z1;
  _Float16* tF2 = tS1 + (size_t)N * HID;

  hipMemsetAsync(d_ws, 0, (size_t)(zero_end - (char*)d_ws), stream);

  const int tpb = 256;
  int etot = E + EK;
  int nbE = (etot + tpb - 1) / tpb;
  k_count_cvt<<<nbE + 96, tpb, 0, stream>>>(col_s, E, cnt_s, col_k, EK, cnt_k, nbE,
                                            W_s1, W_s2, W_f2, Wh);

  int nb = (N + 1023) / 1024;
  dim3 sg(nb, 2);
  k_scan_block2<<<sg, 1024, 0, stream>>>(cnt_s, cnt_k, N, offs_s, offs_k, bsum);
  k_scan_single2<<<1, 64, 0, stream>>>(bsum, nb, offs_s + N, offs_k + N);
  dim3 ag((N + tpb - 1) / tpb, 2);
  k_add_off2<<<ag, tpb, 0, stream>>>(offs_s, offs_k, bsum, N);

  // GEMM fused with CSR scatter (independent; scatter backfills CUs)
  int nbG = (N + 63) / 64;
  k_gemm3_scatter<<<nbG + nbE, 256, 0, stream>>>(
      x, Wh, b_s1, b_s2, b_f2, N, cnt_s, cnt_k, gS1, gS2, gF2s, gF2k,
      row_s, col_s, E, offs_s, cur_s, csr_s,
      row_k, col_k, EK, offs_k, cur_k, csr_k, nbG);

  int spmm_grid = (N + 3) / 4;

  // step 1 (all chains), step 2 (s1 & f2 finalize, s2 continues)
  k_spmm3<<<spmm_grid, 256, 0, stream>>>(gS1, gS2, gF2s,
                                         tS1, tS2, tF2, 0, 0, 0,
                                         csr_s, offs_s, cnt_s, N);
  k_spmm3<<<spmm_grid, 256, 0, stream>>>(tS1, tS2, tF2,
                                         out_h0, gS1, out_z0, 1, 0, 1,
                                         csr_s, offs_s, cnt_s, N);

  // s2 step 3 fused with the knn step (independent work, overlapped)
  k_spmm_dual<<<spmm_grid * 2, 256, 0, stream>>>(
      gS1, tS2, csr_s, offs_s, cnt_s, 0, nullptr,
      gF2k, out_z1, csr_k, offs_k, cnt_k, 2, out_z0,
      spmm_grid, N);

  // s2 steps 4..10: ping-pong tS2 <-> gS1
  {
    _Float16* cur = tS2; _Float16* alt = gS1;
    for (int it = 0; it < 6; ++it) {
      k_spmm_h<<<spmm_grid, 256, 0, stream>>>(cur, alt,
                                              csr_s, offs_s, cnt_s, N, 0, nullptr);
      _Float16* t = cur; cur = alt; alt = t;
    }
    k_spmm_h<<<spmm_grid, 256, 0, stream>>>(cur, out_h1,
                                            csr_s, offs_s, cnt_s, N, 1, nullptr);
  }
}